// Round 11
// baseline (191.400 us; speedup 1.0000x reference)
//
#include <hip/hip_runtime.h>
#include <math.h>

#define NN 20000
#define EE 320000
#define ETOT 340000
#define GG 64
#define INCH 128
#define HIDC 64
#define NH 8
#define HC 512            // NH*HIDC
#define SLOPE 0.2f
#define SMEPS 1e-16f

typedef unsigned short u16;
typedef unsigned int u32;
typedef __attribute__((ext_vector_type(8))) short bf16x8;
typedef __attribute__((ext_vector_type(4))) float f32x4;
typedef __attribute__((ext_vector_type(2))) float f32x2;

__device__ __forceinline__ float rlanef(float v, int l) {
  return __uint_as_float(__builtin_amdgcn_readlane(__float_as_uint(v), l));
}
__device__ __forceinline__ u16 f2bf(float f) {   // round-to-nearest-even
  u32 x = __float_as_uint(f);
  x += 0x7FFFu + ((x >> 16) & 1u);
  return (u16)(x >> 16);
}
__device__ __forceinline__ float bflo(u32 w) { return __uint_as_float(w << 16); }
__device__ __forceinline__ float bfhi(u32 w) { return __uint_as_float(w & 0xffff0000u); }

// ---------------- prep (+ fused edge histogram) ----------------
// blocks [0, PREP_B): W1bf/W2bf/wB1/xbf; blocks [PREP_B, PREP_B+HIST_B): deg histogram
#define PREP_B 10392
#define HIST_B 1329
__global__ void k_prep(const float* __restrict__ W1, const float* __restrict__ W2,
                       const float* __restrict__ as1, const float* __restrict__ ad1v,
                       const float* __restrict__ x, const int* __restrict__ ei,
                       u16* __restrict__ W1bf, u16* __restrict__ W2bf,
                       float* __restrict__ wB1, u16* __restrict__ xbf,
                       int* __restrict__ deg) {
  if (blockIdx.x >= PREP_B) {
    int i = (blockIdx.x - PREP_B) * 256 + threadIdx.x;
    if (i < ETOT) {
      int d = (i < EE) ? ei[EE + i] : (i - EE);
      atomicAdd(&deg[d], 1);
    }
    return;
  }
  int i = blockIdx.x * 256 + threadIdx.x;
  if (i < 65536) {
    W1bf[i] = f2bf(W1[i]);
  } else if (i < 65536 + 32768) {
    int j = i - 65536;
    W2bf[j] = f2bf(W2[j]);
  } else if (i < 65536 + 32768 + 2048) {
    int j = i - 65536 - 32768;   // j = k*16 + c
    int k = j >> 4, c = j & 15;
    int h = c & 7;
    const float* av = (c < 8) ? as1 : ad1v;
    float s = 0.f;
    for (int q = 0; q < 64; ++q) s += W1[(h * 64 + q) * 128 + k] * av[h * 64 + q];
    wB1[j] = s;
  } else {
    int j = i - 100352;
    if (j < NN * INCH) xbf[j] = f2bf(x[j]);
  }
}

// ---------------- scan: 1 block, 2 barriers; thread-serial 20-elem segments ----------
__global__ __launch_bounds__(1024) void k_scan(const int* __restrict__ deg,
                                               int* __restrict__ rowstart) {
  __shared__ int wtot[16];
  int tid = threadIdx.x;
  int lane = tid & 63, w = tid >> 6;
  int base = tid * 20;
  int v[20];
  int s = 0;
#pragma unroll
  for (int k = 0; k < 20; ++k) {
    v[k] = (base + k < NN) ? deg[base + k] : 0;
    s += v[k];
  }
  int ps = s;
#pragma unroll
  for (int off = 1; off < 64; off <<= 1) {
    int t = __shfl_up(ps, off);
    if (lane >= off) ps += t;
  }
  if (lane == 63) wtot[w] = ps;
  __syncthreads();
  if (w == 0 && lane < 16) {
    int t = wtot[lane];
#pragma unroll
    for (int off = 1; off < 16; off <<= 1) {
      int u = __shfl_up(t, off);
      if (lane >= off) t += u;
    }
    wtot[lane] = t;
  }
  __syncthreads();
  int woff = (w == 0) ? 0 : wtot[w - 1];
  int run = woff + ps - s;     // exclusive prefix for this segment
#pragma unroll
  for (int k = 0; k < 20; ++k) {
    run += v[k];
    if (base + k < NN) rowstart[base + k + 1] = run;
  }
  if (tid == 0) rowstart[0] = 0;
}

__global__ void k_fill(const int* __restrict__ ei, const int* __restrict__ rowstart,
                       int* __restrict__ wcur, int* __restrict__ csr) {
  int i = blockIdx.x * 256 + threadIdx.x;
  if (i >= ETOT) return;
  int s, d;
  if (i < EE) { s = ei[i]; d = ei[EE + i]; } else { s = i - EE; d = s; }
  int pos = rowstart[d] + atomicAdd(&wcur[d], 1);
  csr[pos] = s;
}

// ---------------- logits1: al1[n][0..7]=x@wS, [8..15]=x@wD (4 threads / row) ------------
__global__ __launch_bounds__(256) void k_logits1(
    const float* __restrict__ x, const float* __restrict__ wB1,
    float* __restrict__ al1) {
  __shared__ float bs[128][16];
  int tid = threadIdx.x;
#pragma unroll
  for (int i = 0; i < 8; ++i) {
    int e = tid + i * 256;
    bs[e >> 4][e & 15] = wB1[e];
  }
  __syncthreads();
  int gt = blockIdx.x * 256 + tid;
  int r = gt >> 2; if (r > NN - 1) r = NN - 1;
  int q = gt & 3;
  const float* xp = x + (size_t)r * INCH;
  float acc[4] = {0.f, 0.f, 0.f, 0.f};
  for (int kq = 0; kq < 32; ++kq) {
    float4 a = *(const float4*)(xp + kq * 4);
    float av[4] = {a.x, a.y, a.z, a.w};
#pragma unroll
    for (int kk = 0; kk < 4; ++kk) {
      const float4 b = *(const float4*)&bs[kq * 4 + kk][q * 4];
      acc[0] = fmaf(av[kk], b.x, acc[0]);
      acc[1] = fmaf(av[kk], b.y, acc[1]);
      acc[2] = fmaf(av[kk], b.z, acc[2]);
      acc[3] = fmaf(av[kk], b.w, acc[3]);
    }
  }
  float4 o; o.x = acc[0]; o.y = acc[1]; o.z = acc[2]; o.w = acc[3];
  *(float4*)(al1 + (size_t)r * 16 + q * 4) = o;
}

// ---------------- agg1: 2 waves/node (4 heads each), pk_fma + unroll-4, bf16 gather -----
// wave w: node = blk*2 + (w>>1), heads hgrp = (w&1)*4 .. +4; lane owns 2 channels.
// 1-D accumulator arrays ONLY (2-D arrays defeat SROA -> scratch, r6/r7 lesson).
__global__ __launch_bounds__(256) void k_agg1(
    const u16* __restrict__ xbf, const float* __restrict__ al1,
    const int* __restrict__ rowstart, const int* __restrict__ csr,
    u16* __restrict__ aggbf) {
  int wv = threadIdx.x >> 6;
  int n = blockIdx.x * 2 + (wv >> 1);
  int hgrp = (wv & 1) * 4;
  int lane = threadIdx.x & 63;
  int rs = __builtin_amdgcn_readfirstlane(rowstart[n]);
  int re = __builtin_amdgcn_readfirstlane(rowstart[n + 1]);
  float4 ad = *(const float4*)(al1 + (size_t)n * 16 + 8 + hgrp);
  float zp[4] = {};
  f32x2 acc2[4] = {};
  for (int base = rs; base < re; base += 64) {
    int cn = min(64, re - base);
    int idx = base + ((lane < cn) ? lane : 0);
    int s = csr[idx];
    float4 a = *(const float4*)(al1 + (size_t)s * 16 + hgrp);
    float e[4] = {a.x + ad.x, a.y + ad.y, a.z + ad.z, a.w + ad.w};
    float p[4];
#pragma unroll
    for (int h = 0; h < 4; ++h) {
      float t = e[h];
      t = fmaxf(t, SLOPE * t);
      float pv = __expf(t);
      pv = (lane < cn) ? pv : 0.f;
      p[h] = pv;
      zp[h] += pv;
    }
    int j = 0;
    for (; j + 3 < cn; j += 4) {
      int s0 = __builtin_amdgcn_readlane(s, j);
      int s1 = __builtin_amdgcn_readlane(s, j + 1);
      int s2 = __builtin_amdgcn_readlane(s, j + 2);
      int s3 = __builtin_amdgcn_readlane(s, j + 3);
      u32 x0 = *(const u32*)(xbf + (size_t)s0 * INCH + lane * 2);
      u32 x1 = *(const u32*)(xbf + (size_t)s1 * INCH + lane * 2);
      u32 x2 = *(const u32*)(xbf + (size_t)s2 * INCH + lane * 2);
      u32 x3 = *(const u32*)(xbf + (size_t)s3 * INCH + lane * 2);
      f32x2 v0; v0.x = bflo(x0); v0.y = bfhi(x0);
      f32x2 v1; v1.x = bflo(x1); v1.y = bfhi(x1);
      f32x2 v2; v2.x = bflo(x2); v2.y = bfhi(x2);
      f32x2 v3; v3.x = bflo(x3); v3.y = bfhi(x3);
#pragma unroll
      for (int h = 0; h < 4; ++h) {
        float p0 = rlanef(p[h], j);
        float p1 = rlanef(p[h], j + 1);
        float p2 = rlanef(p[h], j + 2);
        float p3 = rlanef(p[h], j + 3);
        f32x2 q0; q0.x = p0; q0.y = p0;
        f32x2 q1; q1.x = p1; q1.y = p1;
        f32x2 q2; q2.x = p2; q2.y = p2;
        f32x2 q3; q3.x = p3; q3.y = p3;
        acc2[h] = __builtin_elementwise_fma(q0, v0, acc2[h]);
        acc2[h] = __builtin_elementwise_fma(q1, v1, acc2[h]);
        acc2[h] = __builtin_elementwise_fma(q2, v2, acc2[h]);
        acc2[h] = __builtin_elementwise_fma(q3, v3, acc2[h]);
      }
    }
    for (; j < cn; ++j) {
      int sa = __builtin_amdgcn_readlane(s, j);
      u32 xa = *(const u32*)(xbf + (size_t)sa * INCH + lane * 2);
      f32x2 va; va.x = bflo(xa); va.y = bfhi(xa);
#pragma unroll
      for (int h = 0; h < 4; ++h) {
        float pa = rlanef(p[h], j);
        f32x2 pa2; pa2.x = pa; pa2.y = pa;
        acc2[h] = __builtin_elementwise_fma(pa2, va, acc2[h]);
      }
    }
  }
#pragma unroll
  for (int h = 0; h < 4; ++h) {
    float z = zp[h];
#pragma unroll
    for (int off = 32; off; off >>= 1) z += __shfl_xor(z, off);
    float inv = 1.f / (z + SMEPS);
    u32 pk = ((u32)f2bf(acc2[h].y * inv) << 16) | (u32)f2bf(acc2[h].x * inv);
    *(u32*)(aggbf + (size_t)(hgrp + h) * NN * INCH + (size_t)n * INCH + lane * 2) = pk;
  }
}

// ---------------- gemm1h: xmid[:, h*64..] = relu(agg_h @ W1_h^T + b1), MFMA bf16 --------
__global__ __launch_bounds__(256) void k_gemm1h(
    const u16* __restrict__ aggbf, const u16* __restrict__ W1bf,
    const float* __restrict__ b1, u16* __restrict__ xmidbf) {
  int tid = threadIdx.x;
  int head = blockIdx.x & 7;
  int nb = blockIdx.x >> 3;
  int w = tid >> 6, l = tid & 63;
  int li = l & 15, hi = l >> 4;
  const u16* Ab = aggbf + (size_t)head * NN * INCH;
  const u16* Bb = W1bf + (size_t)head * 64 * INCH;

  bf16x8 Bf[4][4];   // [ks][ct] (ext_vector + static idx: stays in regs)
#pragma unroll
  for (int ks = 0; ks < 4; ++ks)
#pragma unroll
    for (int ct = 0; ct < 4; ++ct)
      Bf[ks][ct] = *(const bf16x8*)(Bb + (size_t)(ct * 16 + li) * INCH + ks * 32 + hi * 8);

  int nA = nb * 64 + w * 16 + li; if (nA > NN - 1) nA = NN - 1;
  const u16* Ap = Ab + (size_t)nA * INCH + hi * 8;
  f32x4 acc[4] = {};
#pragma unroll
  for (int ks = 0; ks < 4; ++ks) {
    bf16x8 Af = *(const bf16x8*)(Ap + ks * 32);
#pragma unroll
    for (int ct = 0; ct < 4; ++ct)
      acc[ct] = __builtin_amdgcn_mfma_f32_16x16x32_bf16(Af, Bf[ks][ct], acc[ct], 0, 0, 0);
  }
#pragma unroll
  for (int ct = 0; ct < 4; ++ct) {
    float bb = b1[head * 64 + ct * 16 + li];
#pragma unroll
    for (int reg = 0; reg < 4; ++reg) {
      int r = nb * 64 + w * 16 + hi * 4 + reg; if (r > NN - 1) r = NN - 1;
      float v = fmaxf(acc[ct][reg] + bb, 0.f);
      xmidbf[(size_t)r * HC + head * 64 + ct * 16 + li] = f2bf(v);
    }
  }
}

// ---------------- gemm2: h2 = xmid @ W2^T (MFMA bf16, K split over 4 waves) + logits ----
__global__ __launch_bounds__(256) void k_gemm2(
    const u16* __restrict__ xmb, const u16* __restrict__ W2bf,
    const float* __restrict__ atts, const float* __restrict__ attd,
    u16* __restrict__ h2bf, float* __restrict__ as2, float* __restrict__ ad2) {
  __shared__ float red[4][16][65];
  int tid = threadIdx.x;
  int w = tid >> 6, l = tid & 63;
  int li = l & 15, hi = l >> 4;
  int brow = blockIdx.x * 16;     // 1250 blocks * 16 = 20000 exact

  bf16x8 Bf[4][4];
#pragma unroll
  for (int ksl = 0; ksl < 4; ++ksl)
#pragma unroll
    for (int ct = 0; ct < 4; ++ct)
      Bf[ksl][ct] = *(const bf16x8*)(W2bf + (size_t)(ct * 16 + li) * HC + w * 128 + ksl * 32 + hi * 8);

  const u16* Ap = xmb + (size_t)(brow + li) * HC + w * 128 + hi * 8;
  f32x4 acc[4] = {};
#pragma unroll
  for (int ksl = 0; ksl < 4; ++ksl) {
    bf16x8 Af = *(const bf16x8*)(Ap + ksl * 32);
#pragma unroll
    for (int ct = 0; ct < 4; ++ct)
      acc[ct] = __builtin_amdgcn_mfma_f32_16x16x32_bf16(Af, Bf[ksl][ct], acc[ct], 0, 0, 0);
  }
#pragma unroll
  for (int ct = 0; ct < 4; ++ct)
#pragma unroll
    for (int reg = 0; reg < 4; ++reg)
      red[w][hi * 4 + reg][ct * 16 + li] = acc[ct][reg];
  __syncthreads();

  int c = l;                       // wave w handles rows {w, w+4, w+8, w+12}, col c
  float atv = atts[c], adv = attd[c];
  float vs[4], vd[4];
#pragma unroll
  for (int i = 0; i < 4; ++i) {
    int r = w + 4 * i;
    float v = red[0][r][c] + red[1][r][c] + red[2][r][c] + red[3][r][c];
    h2bf[(size_t)(brow + r) * HIDC + c] = f2bf(v);
    vs[i] = v * atv; vd[i] = v * adv;
  }
#pragma unroll
  for (int off = 32; off; off >>= 1) {
#pragma unroll
    for (int i = 0; i < 4; ++i) { vs[i] += __shfl_xor(vs[i], off); vd[i] += __shfl_xor(vd[i], off); }
  }
  if (l == 0) {
#pragma unroll
    for (int i = 0; i < 4; ++i) {
      int n = brow + w + 4 * i;
      as2[n] = vs[i]; ad2[n] = vd[i];
    }
  }
}

// ---------------- node2: wave/node, 4-edge-parallel, pk_fma, unroll-2 -------------------
// lane = e*16 + c : edge slot e, channel block c -> ch c*4..c*4+3
__global__ __launch_bounds__(256) void k_node2(
    const u16* __restrict__ h2bf, const float* __restrict__ as2, const float* __restrict__ ad2,
    const int* __restrict__ rowstart, const int* __restrict__ csr,
    const float* __restrict__ b2, float* __restrict__ out) {
  int n = blockIdx.x * 4 + (threadIdx.x >> 6);
  int lane = threadIdx.x & 63;
  int e = lane >> 4, c = lane & 15;
  int rs = __builtin_amdgcn_readfirstlane(rowstart[n]);
  int re = __builtin_amdgcn_readfirstlane(rowstart[n + 1]);
  float ad = ad2[n];
  f32x2 accA = {}, accB = {};
  float zp = 0.f;
  for (int base = rs; base < re; base += 8) {
    int iA = base + e, iB = base + 4 + e;
    bool okA = iA < re, okB = iB < re;
    int sA = csr[okA ? iA : re - 1];
    int sB = csr[okB ? iB : re - 1];
    float tA = as2[sA] + ad;
    float tB = as2[sB] + ad;
    const u32* hpA = (const u32*)(h2bf + (size_t)sA * HIDC + c * 4);
    const u32* hpB = (const u32*)(h2bf + (size_t)sB * HIDC + c * 4);
    u32 a0 = hpA[0], a1 = hpA[1];
    u32 b0 = hpB[0], b1 = hpB[1];
    tA = fmaxf(tA, SLOPE * tA);
    tB = fmaxf(tB, SLOPE * tB);
    float pA = okA ? __expf(tA) : 0.f;
    float pB = okB ? __expf(tB) : 0.f;
    zp += pA + pB;
    f32x2 vA0; vA0.x = bflo(a0); vA0.y = bfhi(a0);
    f32x2 vA1; vA1.x = bflo(a1); vA1.y = bfhi(a1);
    f32x2 vB0; vB0.x = bflo(b0); vB0.y = bfhi(b0);
    f32x2 vB1; vB1.x = bflo(b1); vB1.y = bfhi(b1);
    f32x2 pA2; pA2.x = pA; pA2.y = pA;
    f32x2 pB2; pB2.x = pB; pB2.y = pB;
    accA = __builtin_elementwise_fma(pA2, vA0, accA);
    accB = __builtin_elementwise_fma(pA2, vA1, accB);
    accA = __builtin_elementwise_fma(pB2, vB0, accA);
    accB = __builtin_elementwise_fma(pB2, vB1, accB);
  }
  float acc0 = accA.x, acc1 = accA.y, acc2v = accB.x, acc3 = accB.y;
  zp += __shfl_xor(zp, 16); zp += __shfl_xor(zp, 32);
  acc0 += __shfl_xor(acc0, 16); acc0 += __shfl_xor(acc0, 32);
  acc1 += __shfl_xor(acc1, 16); acc1 += __shfl_xor(acc1, 32);
  acc2v += __shfl_xor(acc2v, 16); acc2v += __shfl_xor(acc2v, 32);
  acc3 += __shfl_xor(acc3, 16); acc3 += __shfl_xor(acc3, 32);
  if (e == 0) {
    float inv = 1.f / (zp + SMEPS);
    float4 bv = *(const float4*)(b2 + c * 4);
    float4 o;
    o.x = acc0 * inv + bv.x; o.y = acc1 * inv + bv.y;
    o.z = acc2v * inv + bv.z; o.w = acc3 * inv + bv.w;
    *(float4*)(out + (size_t)n * HIDC + c * 4) = o;
  }
}

// ---------------- mean pool: block = (graph, 128-ch chunk) ------------------------------
__device__ inline int lowerb(const int* a, int n, int v) {
  int lo = 0, hi = n;
  while (lo < hi) { int mid = (lo + hi) >> 1; if (a[mid] < v) lo = mid + 1; else hi = mid; }
  return lo;
}

__global__ __launch_bounds__(256) void k_pool(const u16* __restrict__ xmb,
                                              const int* __restrict__ batch,
                                              float* __restrict__ out) {
  __shared__ float red[4][128];
  int g = blockIdx.x >> 2;
  int cb = blockIdx.x & 3;          // 128-ch chunk
  int tid = threadIdx.x;
  int c2 = tid & 63;                // 2 ch via u32
  int rq = tid >> 6;
  int lo = lowerb(batch, NN, g);
  int hi = lowerb(batch, NN, g + 1);
  float sx = 0.f, sy = 0.f;
  for (int n = lo + rq; n < hi; n += 4) {
    u32 w = *(const u32*)(xmb + (size_t)n * HC + cb * 128 + c2 * 2);
    sx += bflo(w); sy += bfhi(w);
  }
  red[rq][c2 * 2] = sx; red[rq][c2 * 2 + 1] = sy;
  __syncthreads();
  if (rq == 0) {
    float inv = 1.f / fmaxf((float)(hi - lo), 1.f);
    float vx = red[0][c2 * 2] + red[1][c2 * 2] + red[2][c2 * 2] + red[3][c2 * 2];
    float vy = red[0][c2 * 2 + 1] + red[1][c2 * 2 + 1] + red[2][c2 * 2 + 1] + red[3][c2 * 2 + 1];
    float2 o; o.x = vx * inv; o.y = vy * inv;
    *(float2*)(out + (size_t)g * HC + cb * 128 + c2 * 2) = o;
  }
}

extern "C" void kernel_launch(void* const* d_in, const int* in_sizes, int n_in,
                              void* d_out, int out_size, void* d_ws, size_t ws_size,
                              hipStream_t stream) {
  const float* x     = (const float*)d_in[0];
  const int*   ei    = (const int*)d_in[1];
  const int*   batch = (const int*)d_in[2];
  const float* W1    = (const float*)d_in[3];
  const float* atts1 = (const float*)d_in[4];
  const float* attd1 = (const float*)d_in[5];
  const float* b1    = (const float*)d_in[6];
  const float* W2    = (const float*)d_in[7];
  const float* atts2 = (const float*)d_in[8];
  const float* attd2 = (const float*)d_in[9];
  const float* b2    = (const float*)d_in[10];
  float* out = (float*)d_out;

  float* ws = (float*)d_ws;
  size_t off = 0;
  u16*  aggbf  = (u16*)(ws + off); off += (size_t)NH * NN * INCH / 2;   // bf16 [8][20000][128]
  u16*  xmidbf = (u16*)(ws + off); off += (size_t)NN * HC / 2;          // bf16 [20000][512]
  u16*  h2bf   = (u16*)(ws + off); off += (size_t)NN * HIDC / 2;        // bf16 [20000][64]
  float* al1  = ws + off; off += (size_t)NN * 16;
  float* as2  = ws + off; off += NN;
  float* ad2  = ws + off; off += NN;
  u16*  W1bf  = (u16*)(ws + off); off += 65536 / 2;
  u16*  W2bf  = (u16*)(ws + off); off += 32768 / 2;
  float* wB1  = ws + off; off += 2048;
  u16*  xbf   = (u16*)(ws + off); off += (size_t)NN * INCH / 2;         // bf16 [20000][128]
  int* deg      = (int*)(ws + off); off += NN;
  int* wcur     = (int*)(ws + off); off += NN;
  int* rowstart = (int*)(ws + off); off += NN + 4;
  int* csr      = (int*)(ws + off); off += ETOT;

  hipMemsetAsync(deg, 0, sizeof(int) * 2 * NN, stream);
  k_prep<<<PREP_B + HIST_B, 256, 0, stream>>>(W1, W2, atts1, attd1, x, ei,
                                              W1bf, W2bf, wB1, xbf, deg);
  k_scan<<<1, 1024, 0, stream>>>(deg, rowstart);
  k_fill<<<(ETOT + 255) / 256, 256, 0, stream>>>(ei, rowstart, wcur, csr);

  k_logits1<<<313, 256, 0, stream>>>(x, wB1, al1);
  k_agg1<<<10000, 256, 0, stream>>>(xbf, al1, rowstart, csr, aggbf);
  k_gemm1h<<<313 * 8, 256, 0, stream>>>(aggbf, W1bf, b1, xmidbf);
  k_pool<<<GG * 4, 256, 0, stream>>>(xmidbf, batch, out);
  k_gemm2<<<1250, 256, 0, stream>>>(xmidbf, W2bf, atts2, attd2, h2bf, as2, ad2);
  k_node2<<<5000, 256, 0, stream>>>(h2bf, as2, ad2, rowstart, csr, b2, out + (size_t)GG * HC);
}

// Round 12
// 179.034 us; speedup vs baseline: 1.0691x; 1.0691x over previous
//
#include <hip/hip_runtime.h>
#include <math.h>

#define NN 20000
#define EE 320000
#define ETOT 340000
#define GG 64
#define INCH 128
#define HIDC 64
#define NH 8
#define HC 512            // NH*HIDC
#define SLOPE 0.2f
#define SMEPS 1e-16f

typedef unsigned short u16;
typedef unsigned int u32;
typedef __attribute__((ext_vector_type(8))) short bf16x8;
typedef __attribute__((ext_vector_type(4))) float f32x4;
typedef __attribute__((ext_vector_type(2))) float f32x2;

__device__ __forceinline__ u16 f2bf(float f) {   // round-to-nearest-even
  u32 x = __float_as_uint(f);
  x += 0x7FFFu + ((x >> 16) & 1u);
  return (u16)(x >> 16);
}
__device__ __forceinline__ float bflo(u32 w) { return __uint_as_float(w << 16); }
__device__ __forceinline__ float bfhi(u32 w) { return __uint_as_float(w & 0xffff0000u); }

// ---------------- prep (+ fused edge histogram) ----------------
#define PREP_B 10392
#define HIST_B 1329
__global__ void k_prep(const float* __restrict__ W1, const float* __restrict__ W2,
                       const float* __restrict__ as1, const float* __restrict__ ad1v,
                       const float* __restrict__ x, const int* __restrict__ ei,
                       u16* __restrict__ W1bf, u16* __restrict__ W2bf,
                       float* __restrict__ wB1, u16* __restrict__ xbf,
                       int* __restrict__ deg) {
  if (blockIdx.x >= PREP_B) {
    int i = (blockIdx.x - PREP_B) * 256 + threadIdx.x;
    if (i < ETOT) {
      int d = (i < EE) ? ei[EE + i] : (i - EE);
      atomicAdd(&deg[d], 1);
    }
    return;
  }
  int i = blockIdx.x * 256 + threadIdx.x;
  if (i < 65536) {
    W1bf[i] = f2bf(W1[i]);
  } else if (i < 65536 + 32768) {
    int j = i - 65536;
    W2bf[j] = f2bf(W2[j]);
  } else if (i < 65536 + 32768 + 2048) {
    int j = i - 65536 - 32768;   // j = k*16 + c
    int k = j >> 4, c = j & 15;
    int h = c & 7;
    const float* av = (c < 8) ? as1 : ad1v;
    float s = 0.f;
    for (int q = 0; q < 64; ++q) s += W1[(h * 64 + q) * 128 + k] * av[h * 64 + q];
    wB1[j] = s;
  } else {
    int j = i - 100352;
    if (j < NN * INCH) xbf[j] = f2bf(x[j]);
  }
}

// ---------------- scan: 1 block, 2 barriers; thread-serial 20-elem segments ----------
__global__ __launch_bounds__(1024) void k_scan(const int* __restrict__ deg,
                                               int* __restrict__ rowstart) {
  __shared__ int wtot[16];
  int tid = threadIdx.x;
  int lane = tid & 63, w = tid >> 6;
  int base = tid * 20;
  int v[20];
  int s = 0;
#pragma unroll
  for (int k = 0; k < 20; ++k) {
    v[k] = (base + k < NN) ? deg[base + k] : 0;
    s += v[k];
  }
  int ps = s;
#pragma unroll
  for (int off = 1; off < 64; off <<= 1) {
    int t = __shfl_up(ps, off);
    if (lane >= off) ps += t;
  }
  if (lane == 63) wtot[w] = ps;
  __syncthreads();
  if (w == 0 && lane < 16) {
    int t = wtot[lane];
#pragma unroll
    for (int off = 1; off < 16; off <<= 1) {
      int u = __shfl_up(t, off);
      if (lane >= off) t += u;
    }
    wtot[lane] = t;
  }
  __syncthreads();
  int woff = (w == 0) ? 0 : wtot[w - 1];
  int run = woff + ps - s;     // exclusive prefix for this segment
#pragma unroll
  for (int k = 0; k < 20; ++k) {
    run += v[k];
    if (base + k < NN) rowstart[base + k + 1] = run;
  }
  if (tid == 0) rowstart[0] = 0;
}

// ---------------- fill + logits1 merged (independent work, block-range split) -----------
#define FILL_B 1329
__global__ __launch_bounds__(256) void k_fill_logits(
    const int* __restrict__ ei, const int* __restrict__ rowstart,
    int* __restrict__ wcur, int* __restrict__ csr,
    const float* __restrict__ x, const float* __restrict__ wB1,
    float* __restrict__ al1) {
  __shared__ float bs[128][16];
  int tid = threadIdx.x;
  if (blockIdx.x < FILL_B) {
    int i = blockIdx.x * 256 + tid;
    if (i >= ETOT) return;
    int s, d;
    if (i < EE) { s = ei[i]; d = ei[EE + i]; } else { s = i - EE; d = s; }
    int pos = rowstart[d] + atomicAdd(&wcur[d], 1);
    csr[pos] = s;
    return;
  }
#pragma unroll
  for (int i = 0; i < 8; ++i) {
    int e = tid + i * 256;
    bs[e >> 4][e & 15] = wB1[e];
  }
  __syncthreads();
  int gt = (blockIdx.x - FILL_B) * 256 + tid;
  int r = gt >> 2; if (r > NN - 1) r = NN - 1;
  int q = gt & 3;
  const float* xp = x + (size_t)r * INCH;
  float acc[4] = {0.f, 0.f, 0.f, 0.f};
  for (int kq = 0; kq < 32; ++kq) {
    float4 a = *(const float4*)(xp + kq * 4);
    float av[4] = {a.x, a.y, a.z, a.w};
#pragma unroll
    for (int kk = 0; kk < 4; ++kk) {
      const float4 b = *(const float4*)&bs[kq * 4 + kk][q * 4];
      acc[0] = fmaf(av[kk], b.x, acc[0]);
      acc[1] = fmaf(av[kk], b.y, acc[1]);
      acc[2] = fmaf(av[kk], b.z, acc[2]);
      acc[3] = fmaf(av[kk], b.w, acc[3]);
    }
  }
  float4 o; o.x = acc[0]; o.y = acc[1]; o.z = acc[2]; o.w = acc[3];
  *(float4*)(al1 + (size_t)r * 16 + q * 4) = o;
}

// ---------------- agg1: wave/node, LDS p-broadcast + unroll-4, bf16 x gather ------------
// lane = channel pair owner (2 ch); p computed per-lane (lane=edge in chunk), staged to
// LDS once per chunk, then broadcast-read (2x ds_read_b128 per edge replaces 8 readlanes).
// Accumulators: 1-D f32x2 arrays only (2-D defeats SROA -> scratch, r6/r7 lesson).
#define PSTR 12   // stride in floats: 48B -> 16B-aligned for b128 reads
__global__ __launch_bounds__(256) void k_agg1(
    const u16* __restrict__ xbf, const float* __restrict__ al1,
    const int* __restrict__ rowstart, const int* __restrict__ csr,
    u16* __restrict__ aggbf) {
  __shared__ float p_sh[4][64 * PSTR];
  int wv = threadIdx.x >> 6;
  int n = blockIdx.x * 4 + wv;
  int lane = threadIdx.x & 63;
  int rs = __builtin_amdgcn_readfirstlane(rowstart[n]);
  int re = __builtin_amdgcn_readfirstlane(rowstart[n + 1]);
  float4 ad0 = *(const float4*)(al1 + (size_t)n * 16 + 8);
  float4 ad1 = *(const float4*)(al1 + (size_t)n * 16 + 12);
  float zp[NH] = {};
  f32x2 acc2[NH] = {};
  float* pw = &p_sh[wv][0];
  for (int base = rs; base < re; base += 64) {
    int cn = min(64, re - base);
    int idx = base + ((lane < cn) ? lane : 0);
    int s = csr[idx];
    float4 a0 = *(const float4*)(al1 + (size_t)s * 16);
    float4 a1 = *(const float4*)(al1 + (size_t)s * 16 + 4);
    float e[8] = {a0.x + ad0.x, a0.y + ad0.y, a0.z + ad0.z, a0.w + ad0.w,
                  a1.x + ad1.x, a1.y + ad1.y, a1.z + ad1.z, a1.w + ad1.w};
    float p[8];
#pragma unroll
    for (int h = 0; h < 8; ++h) {
      float t = e[h];
      t = fmaxf(t, SLOPE * t);
      float pv = __expf(t);
      pv = (lane < cn) ? pv : 0.f;
      p[h] = pv;
      zp[h] += pv;
    }
    {
      float* pd = pw + lane * PSTR;
      f32x4 w0; w0.x = p[0]; w0.y = p[1]; w0.z = p[2]; w0.w = p[3];
      f32x4 w1; w1.x = p[4]; w1.y = p[5]; w1.z = p[6]; w1.w = p[7];
      *(f32x4*)(pd) = w0;
      *(f32x4*)(pd + 4) = w1;
    }
    int j = 0;
    for (; j + 3 < cn; j += 4) {
      int s0 = __builtin_amdgcn_readlane(s, j);
      int s1 = __builtin_amdgcn_readlane(s, j + 1);
      int s2 = __builtin_amdgcn_readlane(s, j + 2);
      int s3 = __builtin_amdgcn_readlane(s, j + 3);
      u32 x0 = *(const u32*)(xbf + (size_t)s0 * INCH + lane * 2);
      u32 x1 = *(const u32*)(xbf + (size_t)s1 * INCH + lane * 2);
      u32 x2 = *(const u32*)(xbf + (size_t)s2 * INCH + lane * 2);
      u32 x3 = *(const u32*)(xbf + (size_t)s3 * INCH + lane * 2);
      f32x4 pA0 = *(const f32x4*)(pw + (j + 0) * PSTR);
      f32x4 pA1 = *(const f32x4*)(pw + (j + 0) * PSTR + 4);
      f32x4 pB0 = *(const f32x4*)(pw + (j + 1) * PSTR);
      f32x4 pB1 = *(const f32x4*)(pw + (j + 1) * PSTR + 4);
      f32x4 pC0 = *(const f32x4*)(pw + (j + 2) * PSTR);
      f32x4 pC1 = *(const f32x4*)(pw + (j + 2) * PSTR + 4);
      f32x4 pD0 = *(const f32x4*)(pw + (j + 3) * PSTR);
      f32x4 pD1 = *(const f32x4*)(pw + (j + 3) * PSTR + 4);
      f32x2 v0; v0.x = bflo(x0); v0.y = bfhi(x0);
      f32x2 v1; v1.x = bflo(x1); v1.y = bfhi(x1);
      f32x2 v2; v2.x = bflo(x2); v2.y = bfhi(x2);
      f32x2 v3; v3.x = bflo(x3); v3.y = bfhi(x3);
#pragma unroll
      for (int h = 0; h < 4; ++h) {
        f32x2 qA; qA.x = pA0[h]; qA.y = pA0[h];
        f32x2 qB; qB.x = pB0[h]; qB.y = pB0[h];
        f32x2 qC; qC.x = pC0[h]; qC.y = pC0[h];
        f32x2 qD; qD.x = pD0[h]; qD.y = pD0[h];
        acc2[h] = __builtin_elementwise_fma(qA, v0, acc2[h]);
        acc2[h] = __builtin_elementwise_fma(qB, v1, acc2[h]);
        acc2[h] = __builtin_elementwise_fma(qC, v2, acc2[h]);
        acc2[h] = __builtin_elementwise_fma(qD, v3, acc2[h]);
      }
#pragma unroll
      for (int h = 0; h < 4; ++h) {
        f32x2 qA; qA.x = pA1[h]; qA.y = pA1[h];
        f32x2 qB; qB.x = pB1[h]; qB.y = pB1[h];
        f32x2 qC; qC.x = pC1[h]; qC.y = pC1[h];
        f32x2 qD; qD.x = pD1[h]; qD.y = pD1[h];
        acc2[4 + h] = __builtin_elementwise_fma(qA, v0, acc2[4 + h]);
        acc2[4 + h] = __builtin_elementwise_fma(qB, v1, acc2[4 + h]);
        acc2[4 + h] = __builtin_elementwise_fma(qC, v2, acc2[4 + h]);
        acc2[4 + h] = __builtin_elementwise_fma(qD, v3, acc2[4 + h]);
      }
    }
    for (; j < cn; ++j) {
      int sa = __builtin_amdgcn_readlane(s, j);
      u32 xa = *(const u32*)(xbf + (size_t)sa * INCH + lane * 2);
      f32x4 pA0 = *(const f32x4*)(pw + j * PSTR);
      f32x4 pA1 = *(const f32x4*)(pw + j * PSTR + 4);
      f32x2 va; va.x = bflo(xa); va.y = bfhi(xa);
#pragma unroll
      for (int h = 0; h < 4; ++h) {
        f32x2 qA; qA.x = pA0[h]; qA.y = pA0[h];
        acc2[h] = __builtin_elementwise_fma(qA, va, acc2[h]);
      }
#pragma unroll
      for (int h = 0; h < 4; ++h) {
        f32x2 qA; qA.x = pA1[h]; qA.y = pA1[h];
        acc2[4 + h] = __builtin_elementwise_fma(qA, va, acc2[4 + h]);
      }
    }
  }
#pragma unroll
  for (int h = 0; h < 8; ++h) {
    float z = zp[h];
#pragma unroll
    for (int off = 32; off; off >>= 1) z += __shfl_xor(z, off);
    float inv = 1.f / (z + SMEPS);
    u32 pk = ((u32)f2bf(acc2[h].y * inv) << 16) | (u32)f2bf(acc2[h].x * inv);
    *(u32*)(aggbf + (size_t)h * NN * INCH + (size_t)n * INCH + lane * 2) = pk;
  }
}

// ---------------- gemm1h: xmid[:, h*64..] = relu(agg_h @ W1_h^T + b1), MFMA bf16 --------
__global__ __launch_bounds__(256) void k_gemm1h(
    const u16* __restrict__ aggbf, const u16* __restrict__ W1bf,
    const float* __restrict__ b1, u16* __restrict__ xmidbf) {
  int tid = threadIdx.x;
  int head = blockIdx.x & 7;
  int nb = blockIdx.x >> 3;
  int w = tid >> 6, l = tid & 63;
  int li = l & 15, hi = l >> 4;
  const u16* Ab = aggbf + (size_t)head * NN * INCH;
  const u16* Bb = W1bf + (size_t)head * 64 * INCH;

  bf16x8 Bf[4][4];   // [ks][ct] (ext_vector + static idx: stays in regs)
#pragma unroll
  for (int ks = 0; ks < 4; ++ks)
#pragma unroll
    for (int ct = 0; ct < 4; ++ct)
      Bf[ks][ct] = *(const bf16x8*)(Bb + (size_t)(ct * 16 + li) * INCH + ks * 32 + hi * 8);

  int nA = nb * 64 + w * 16 + li; if (nA > NN - 1) nA = NN - 1;
  const u16* Ap = Ab + (size_t)nA * INCH + hi * 8;
  f32x4 acc[4] = {};
#pragma unroll
  for (int ks = 0; ks < 4; ++ks) {
    bf16x8 Af = *(const bf16x8*)(Ap + ks * 32);
#pragma unroll
    for (int ct = 0; ct < 4; ++ct)
      acc[ct] = __builtin_amdgcn_mfma_f32_16x16x32_bf16(Af, Bf[ks][ct], acc[ct], 0, 0, 0);
  }
#pragma unroll
  for (int ct = 0; ct < 4; ++ct) {
    float bb = b1[head * 64 + ct * 16 + li];
#pragma unroll
    for (int reg = 0; reg < 4; ++reg) {
      int r = nb * 64 + w * 16 + hi * 4 + reg; if (r > NN - 1) r = NN - 1;
      float v = fmaxf(acc[ct][reg] + bb, 0.f);
      xmidbf[(size_t)r * HC + head * 64 + ct * 16 + li] = f2bf(v);
    }
  }
}

// ---------------- gemm2 + pool merged (both read xmid; independent outputs) -------------
#define G2_B 1250
__device__ inline int lowerb(const int* a, int n, int v) {
  int lo = 0, hi = n;
  while (lo < hi) { int mid = (lo + hi) >> 1; if (a[mid] < v) lo = mid + 1; else hi = mid; }
  return lo;
}

__global__ __launch_bounds__(256) void k_gemm2_pool(
    const u16* __restrict__ xmb, const u16* __restrict__ W2bf,
    const float* __restrict__ atts, const float* __restrict__ attd,
    u16* __restrict__ h2bf, float* __restrict__ as2, float* __restrict__ ad2,
    const int* __restrict__ batch, float* __restrict__ out) {
  __shared__ float red[4][16][65];
  __shared__ float redp[4][128];
  int tid = threadIdx.x;
  if (blockIdx.x >= G2_B) {
    // ---- pool: block = (graph, 128-ch chunk) ----
    int bid = blockIdx.x - G2_B;
    int g = bid >> 2;
    int cb = bid & 3;
    int c2 = tid & 63;
    int rq = tid >> 6;
    int lo = lowerb(batch, NN, g);
    int hi = lowerb(batch, NN, g + 1);
    float sx = 0.f, sy = 0.f;
    for (int n = lo + rq; n < hi; n += 4) {
      u32 w = *(const u32*)(xmb + (size_t)n * HC + cb * 128 + c2 * 2);
      sx += bflo(w); sy += bfhi(w);
    }
    redp[rq][c2 * 2] = sx; redp[rq][c2 * 2 + 1] = sy;
    __syncthreads();
    if (rq == 0) {
      float inv = 1.f / fmaxf((float)(hi - lo), 1.f);
      float vx = redp[0][c2 * 2] + redp[1][c2 * 2] + redp[2][c2 * 2] + redp[3][c2 * 2];
      float vy = redp[0][c2 * 2 + 1] + redp[1][c2 * 2 + 1] + redp[2][c2 * 2 + 1] + redp[3][c2 * 2 + 1];
      float2 o; o.x = vx * inv; o.y = vy * inv;
      *(float2*)(out + (size_t)g * HC + cb * 128 + c2 * 2) = o;
    }
    return;
  }
  // ---- gemm2 ----
  int w = tid >> 6, l = tid & 63;
  int li = l & 15, hi = l >> 4;
  int brow = blockIdx.x * 16;     // 1250 blocks * 16 = 20000 exact

  bf16x8 Bf[4][4];
#pragma unroll
  for (int ksl = 0; ksl < 4; ++ksl)
#pragma unroll
    for (int ct = 0; ct < 4; ++ct)
      Bf[ksl][ct] = *(const bf16x8*)(W2bf + (size_t)(ct * 16 + li) * HC + w * 128 + ksl * 32 + hi * 8);

  const u16* Ap = xmb + (size_t)(brow + li) * HC + w * 128 + hi * 8;
  f32x4 acc[4] = {};
#pragma unroll
  for (int ksl = 0; ksl < 4; ++ksl) {
    bf16x8 Af = *(const bf16x8*)(Ap + ksl * 32);
#pragma unroll
    for (int ct = 0; ct < 4; ++ct)
      acc[ct] = __builtin_amdgcn_mfma_f32_16x16x32_bf16(Af, Bf[ksl][ct], acc[ct], 0, 0, 0);
  }
#pragma unroll
  for (int ct = 0; ct < 4; ++ct)
#pragma unroll
    for (int reg = 0; reg < 4; ++reg)
      red[w][hi * 4 + reg][ct * 16 + li] = acc[ct][reg];
  __syncthreads();

  int c = l;                       // wave w handles rows {w, w+4, w+8, w+12}, col c
  float atv = atts[c], adv = attd[c];
  float vs[4], vd[4];
#pragma unroll
  for (int i = 0; i < 4; ++i) {
    int r = w + 4 * i;
    float v = red[0][r][c] + red[1][r][c] + red[2][r][c] + red[3][r][c];
    h2bf[(size_t)(brow + r) * HIDC + c] = f2bf(v);
    vs[i] = v * atv; vd[i] = v * adv;
  }
#pragma unroll
  for (int off = 32; off; off >>= 1) {
#pragma unroll
    for (int i = 0; i < 4; ++i) { vs[i] += __shfl_xor(vs[i], off); vd[i] += __shfl_xor(vd[i], off); }
  }
  if (l == 0) {
#pragma unroll
    for (int i = 0; i < 4; ++i) {
      int n = brow + w + 4 * i;
      as2[n] = vs[i]; ad2[n] = vd[i];
    }
  }
}

// ---------------- node2: wave/node, 4-edge-parallel, pk_fma, unroll-2 -------------------
__global__ __launch_bounds__(256) void k_node2(
    const u16* __restrict__ h2bf, const float* __restrict__ as2, const float* __restrict__ ad2,
    const int* __restrict__ rowstart, const int* __restrict__ csr,
    const float* __restrict__ b2, float* __restrict__ out) {
  int n = blockIdx.x * 4 + (threadIdx.x >> 6);
  int lane = threadIdx.x & 63;
  int e = lane >> 4, c = lane & 15;
  int rs = __builtin_amdgcn_readfirstlane(rowstart[n]);
  int re = __builtin_amdgcn_readfirstlane(rowstart[n + 1]);
  float ad = ad2[n];
  f32x2 accA = {}, accB = {};
  float zp = 0.f;
  for (int base = rs; base < re; base += 8) {
    int iA = base + e, iB = base + 4 + e;
    bool okA = iA < re, okB = iB < re;
    int sA = csr[okA ? iA : re - 1];
    int sB = csr[okB ? iB : re - 1];
    float tA = as2[sA] + ad;
    float tB = as2[sB] + ad;
    const u32* hpA = (const u32*)(h2bf + (size_t)sA * HIDC + c * 4);
    const u32* hpB = (const u32*)(h2bf + (size_t)sB * HIDC + c * 4);
    u32 a0 = hpA[0], a1 = hpA[1];
    u32 b0 = hpB[0], b1 = hpB[1];
    tA = fmaxf(tA, SLOPE * tA);
    tB = fmaxf(tB, SLOPE * tB);
    float pA = okA ? __expf(tA) : 0.f;
    float pB = okB ? __expf(tB) : 0.f;
    zp += pA + pB;
    f32x2 vA0; vA0.x = bflo(a0); vA0.y = bfhi(a0);
    f32x2 vA1; vA1.x = bflo(a1); vA1.y = bfhi(a1);
    f32x2 vB0; vB0.x = bflo(b0); vB0.y = bfhi(b0);
    f32x2 vB1; vB1.x = bflo(b1); vB1.y = bfhi(b1);
    f32x2 pA2; pA2.x = pA; pA2.y = pA;
    f32x2 pB2; pB2.x = pB; pB2.y = pB;
    accA = __builtin_elementwise_fma(pA2, vA0, accA);
    accB = __builtin_elementwise_fma(pA2, vA1, accB);
    accA = __builtin_elementwise_fma(pB2, vB0, accA);
    accB = __builtin_elementwise_fma(pB2, vB1, accB);
  }
  float acc0 = accA.x, acc1 = accA.y, acc2v = accB.x, acc3 = accB.y;
  zp += __shfl_xor(zp, 16); zp += __shfl_xor(zp, 32);
  acc0 += __shfl_xor(acc0, 16); acc0 += __shfl_xor(acc0, 32);
  acc1 += __shfl_xor(acc1, 16); acc1 += __shfl_xor(acc1, 32);
  acc2v += __shfl_xor(acc2v, 16); acc2v += __shfl_xor(acc2v, 32);
  acc3 += __shfl_xor(acc3, 16); acc3 += __shfl_xor(acc3, 32);
  if (e == 0) {
    float inv = 1.f / (zp + SMEPS);
    float4 bv = *(const float4*)(b2 + c * 4);
    float4 o;
    o.x = acc0 * inv + bv.x; o.y = acc1 * inv + bv.y;
    o.z = acc2v * inv + bv.z; o.w = acc3 * inv + bv.w;
    *(float4*)(out + (size_t)n * HIDC + c * 4) = o;
  }
}

extern "C" void kernel_launch(void* const* d_in, const int* in_sizes, int n_in,
                              void* d_out, int out_size, void* d_ws, size_t ws_size,
                              hipStream_t stream) {
  const float* x     = (const float*)d_in[0];
  const int*   ei    = (const int*)d_in[1];
  const int*   batch = (const int*)d_in[2];
  const float* W1    = (const float*)d_in[3];
  const float* atts1 = (const float*)d_in[4];
  const float* attd1 = (const float*)d_in[5];
  const float* b1    = (const float*)d_in[6];
  const float* W2    = (const float*)d_in[7];
  const float* atts2 = (const float*)d_in[8];
  const float* attd2 = (const float*)d_in[9];
  const float* b2    = (const float*)d_in[10];
  float* out = (float*)d_out;

  float* ws = (float*)d_ws;
  size_t off = 0;
  u16*  aggbf  = (u16*)(ws + off); off += (size_t)NH * NN * INCH / 2;   // bf16 [8][20000][128]
  u16*  xmidbf = (u16*)(ws + off); off += (size_t)NN * HC / 2;          // bf16 [20000][512]
  u16*  h2bf   = (u16*)(ws + off); off += (size_t)NN * HIDC / 2;        // bf16 [20000][64]
  float* al1  = ws + off; off += (size_t)NN * 16;
  float* as2  = ws + off; off += NN;
  float* ad2  = ws + off; off += NN;
  u16*  W1bf  = (u16*)(ws + off); off += 65536 / 2;
  u16*  W2bf  = (u16*)(ws + off); off += 32768 / 2;
  float* wB1  = ws + off; off += 2048;
  u16*  xbf   = (u16*)(ws + off); off += (size_t)NN * INCH / 2;         // bf16 [20000][128]
  int* deg      = (int*)(ws + off); off += NN;
  int* wcur     = (int*)(ws + off); off += NN;
  int* rowstart = (int*)(ws + off); off += NN + 4;
  int* csr      = (int*)(ws + off); off += ETOT;

  hipMemsetAsync(deg, 0, sizeof(int) * 2 * NN, stream);
  k_prep<<<PREP_B + HIST_B, 256, 0, stream>>>(W1, W2, atts1, attd1, x, ei,
                                              W1bf, W2bf, wB1, xbf, deg);
  k_scan<<<1, 1024, 0, stream>>>(deg, rowstart);
  k_fill_logits<<<FILL_B + 313, 256, 0, stream>>>(ei, rowstart, wcur, csr, x, wB1, al1);
  k_agg1<<<5000, 256, 0, stream>>>(xbf, al1, rowstart, csr, aggbf);
  k_gemm1h<<<313 * 8, 256, 0, stream>>>(aggbf, W1bf, b1, xmidbf);
  k_gemm2_pool<<<G2_B + GG * 4, 256, 0, stream>>>(xmidbf, W2bf, atts2, attd2,
                                                  h2bf, as2, ad2, batch, out);
  k_node2<<<5000, 256, 0, stream>>>(h2bf, as2, ad2, rowstart, csr, b2, out + (size_t)GG * HC);
}